// Round 3
// baseline (944.374 us; speedup 1.0000x reference)
//
#include <hip/hip_runtime.h>
#include <hip/hip_bf16.h>
#include <math.h>

#define B_SZ 64
#define NQ   512
#define NV   1024
#define QD   768
#define VD   512
#define HIDD 512

typedef __bf16 bf16x8 __attribute__((ext_vector_type(8)));
typedef __bf16 bf16x4 __attribute__((ext_vector_type(4)));
typedef float  floatx4 __attribute__((ext_vector_type(4)));

// async global->LDS, 16 bytes per lane; LDS dest is wave-uniform base,
// HW writes lane l at base + l*16 (linear). Swizzle applied on the global
// SOURCE col (gksw) + the LDS READ (fo) -- both-sides involution.
__device__ __forceinline__ void g2lds16(const __bf16* g, __bf16* l) {
    __builtin_amdgcn_global_load_lds((const __attribute__((address_space(1))) void*)g,
                                     (__attribute__((address_space(3))) void*)l,
                                     16, 0, 0);
}

// exp(tanh(s)) = e^(1 - 2/(e^{2s}+1)); saturates correctly as e^{2s}->0/inf.
__device__ __forceinline__ float exptanh(float s) {
    float t = __expf(2.0f * s);
    float r = __builtin_amdgcn_rcpf(t + 1.0f);
    return __expf(1.0f - 2.0f * r);
}

// ---------------------------------------------------------------------------
// fp32 -> bf16 convert for both weight matrices in one launch (dests adjacent).
__global__ __launch_bounds__(256) void cvt2_k(const float* __restrict__ s0,
                                              const float* __restrict__ s1,
                                              __bf16* __restrict__ d,
                                              int n4a, int n4tot) {
    int i = blockIdx.x * 256 + threadIdx.x;
    if (i >= n4tot) return;
    const float* s = (i < n4a) ? (s0 + (size_t)i * 4) : (s1 + (size_t)(i - n4a) * 4);
    float4 f = *(const float4*)s;
    bf16x4 o;
    o[0] = (__bf16)f.x; o[1] = (__bf16)f.y; o[2] = (__bf16)f.z; o[3] = (__bf16)f.w;
    *(bf16x4*)(d + (size_t)i * 4) = o;
}

// ---------------------------------------------------------------------------
// Projection GEMM, Q and V fused (blocks < nqblk do Q). Block = 128 rows x
// ALL 512 cols, 512 threads / 8 waves, each wave 64x128 (acc 4x8).
// LDS 80 KB -> 2 blocks/CU = 16 waves/CU (vs 8 before: latency hiding).
// W traffic per output row halved vs 64-row blocks. 2-phase dbuf schedule.
__global__ __launch_bounds__(512, 4) void proj_k(
    const float* __restrict__ Qin, const float* __restrict__ Vin,
    const __bf16* __restrict__ Wqb, const __bf16* __restrict__ Wvb,
    const float* __restrict__ bq, const float* __restrict__ bv,
    __bf16* __restrict__ Qp, __bf16* __restrict__ Vp)
{
    __shared__ __bf16 As[2][128 * 32];   // 16 KB
    __shared__ __bf16 Bs[2][512 * 32];   // 64 KB
    const int nqblk = (B_SZ * NQ) / 128;   // 256
    const float* A; const __bf16* W; const float* bias; __bf16* Cout; int K, mblk;
    if ((int)blockIdx.x < nqblk) {
        A = Qin; W = Wqb; bias = bq; Cout = Qp; K = QD; mblk = blockIdx.x;
    } else {
        A = Vin; W = Wvb; bias = bv; Cout = Vp; K = VD; mblk = blockIdx.x - nqblk;
    }

    const int t = threadIdx.x, lane = t & 63, wave = t >> 6;
    const int fr = lane & 15, quad = lane >> 4;
    const int fo   = (quad ^ ((fr >> 1) & 3)) * 8;            // swizzled frag read
    const int gksw = ((lane & 3) ^ ((lane >> 3) & 3)) * 8;    // pre-swizzled src col
    const int tile_m = mblk * 128;
    const int wm = (wave >> 2) * 64;     // 0 / 64
    const int wn = (wave & 3) * 128;     // 0..384

    // W staging: wave covers rows [wave*64, wave*64+64) in 4 g2lds of 16 rows
    const __bf16* wsrc = W + (size_t)(wave * 64 + (lane >> 2)) * K + gksw;
    // A staging: thread t handles row t>>2 (0..127), slot t&3 (8 fp32 elems)
    const int arow = t >> 2, aslot = t & 3;
    const float* ap = A + (size_t)(tile_m + arow) * K + aslot * 8;
    const int awoff = arow * 32 + ((aslot ^ ((arow >> 1) & 3)) * 8);

    floatx4 acc[4][8] = {};

    auto stage_w = [&](int p, int k0) {
        #pragma unroll
        for (int c = 0; c < 4; c++)
            g2lds16(wsrc + (size_t)(c * 16) * K + k0, &Bs[p][(wave * 64 + c * 16) * 32]);
    };
    auto cvt_a = [&](int p, float4 f0, float4 f1) {
        bf16x8 pk;
        pk[0] = (__bf16)f0.x; pk[1] = (__bf16)f0.y; pk[2] = (__bf16)f0.z; pk[3] = (__bf16)f0.w;
        pk[4] = (__bf16)f1.x; pk[5] = (__bf16)f1.y; pk[6] = (__bf16)f1.z; pk[7] = (__bf16)f1.w;
        *(bf16x8*)&As[p][awoff] = pk;
    };
    auto compute = [&](int p) {
        bf16x8 af[4];
        #pragma unroll
        for (int i = 0; i < 4; i++)
            af[i] = *(const bf16x8*)&As[p][(wm + 16 * i + fr) * 32 + fo];
        #pragma unroll
        for (int j = 0; j < 8; j++) {
            bf16x8 bg = *(const bf16x8*)&Bs[p][(wn + 16 * j + fr) * 32 + fo];
            #pragma unroll
            for (int i = 0; i < 4; i++)
                acc[i][j] = __builtin_amdgcn_mfma_f32_16x16x32_bf16(af[i], bg, acc[i][j], 0, 0, 0);
        }
    };

    {
        float4 f0 = *(const float4*)(ap);
        float4 f1 = *(const float4*)(ap + 4);
        stage_w(0, 0);
        cvt_a(0, f0, f1);
    }
    __syncthreads();
    int cur = 0;
    for (int k0 = 32; k0 < K; k0 += 32) {
        float4 f0 = *(const float4*)(ap + k0);       // A prefetch (global->reg)
        float4 f1 = *(const float4*)(ap + k0 + 4);
        const int nxt = cur ^ 1;
        stage_w(nxt, k0);                            // in flight across compute
        compute(cur);
        cvt_a(nxt, f0, f1);
        __syncthreads();
        cur = nxt;
    }
    compute(cur);

    #pragma unroll
    for (int j = 0; j < 8; j++) {
        const int col = wn + 16 * j + fr;
        const float bvv = bias[col];
        #pragma unroll
        for (int i = 0; i < 4; i++)
            #pragma unroll
            for (int r = 0; r < 4; r++) {
                const int row = tile_m + wm + 16 * i + quad * 4 + r;
                Cout[(size_t)row * HIDD + col] = (__bf16)(acc[i][j][r] + bvv);
            }
    }
}

// ---------------------------------------------------------------------------
// Per batch: S = Qp[b] @ Vp[b]^T on a 256x256 tile, 512 thr / 8 waves
// (wave = 64x128, acc 4x8); E = exp(tanh(S)) -> bf16; row sums -> R,
// col sums -> C (atomics). XCD-swizzled 1D grid: each XCD owns 8 batches
// (Qp/Vp panels become XCD-L2 resident). LDS 64 KB -> 2 blocks/CU.
__global__ __launch_bounds__(512, 4) void gemm_h(
    const __bf16* __restrict__ Qp, const __bf16* __restrict__ Vp,
    __bf16* __restrict__ Eg, float* __restrict__ R, float* __restrict__ Csum)
{
    __shared__ __bf16 As[2][256 * 32];   // 32 KB
    __shared__ __bf16 Bs[2][256 * 32];   // 32 KB
    // bijective XCD swizzle: 512 blocks, 8 XCDs, 64 chunks each.
    const int swz   = ((int)blockIdx.x & 7) * 64 + ((int)blockIdx.x >> 3);
    const int b      = swz >> 3;
    const int tile_v = (swz & 3) * 256;
    const int tile_q = ((swz >> 2) & 1) * 256;
    const int t = threadIdx.x, lane = t & 63, wave = t >> 6;
    const int fr = lane & 15, quad = lane >> 4;
    const int fo   = (quad ^ ((fr >> 1) & 3)) * 8;
    const int gksw = ((lane & 3) ^ ((lane >> 3) & 3)) * 8;
    const int wm = (wave >> 1) * 64, wn = (wave & 1) * 128;

    // staging: each wave covers 32 rows of A-tile and 32 rows of B-tile
    const __bf16* Aq = Qp + ((size_t)b * NQ + tile_q + wave * 32 + (lane >> 2)) * HIDD + gksw;
    const __bf16* Bv = Vp + ((size_t)b * NV + tile_v + wave * 32 + (lane >> 2)) * HIDD + gksw;

    auto stage = [&](int p, int k0) {
        #pragma unroll
        for (int c = 0; c < 2; c++)
            g2lds16(Aq + (size_t)(c * 16) * HIDD + k0, &As[p][(wave * 32 + c * 16) * 32]);
        #pragma unroll
        for (int c = 0; c < 2; c++)
            g2lds16(Bv + (size_t)(c * 16) * HIDD + k0, &Bs[p][(wave * 32 + c * 16) * 32]);
    };

    floatx4 acc[4][8] = {};
    auto compute = [&](int p) {
        bf16x8 af[4];
        #pragma unroll
        for (int i = 0; i < 4; i++)
            af[i] = *(const bf16x8*)&As[p][(wm + 16 * i + fr) * 32 + fo];
        #pragma unroll
        for (int j = 0; j < 8; j++) {
            bf16x8 bg = *(const bf16x8*)&Bs[p][(wn + 16 * j + fr) * 32 + fo];
            #pragma unroll
            for (int i = 0; i < 4; i++)
                acc[i][j] = __builtin_amdgcn_mfma_f32_16x16x32_bf16(af[i], bg, acc[i][j], 0, 0, 0);
        }
    };

    stage(0, 0);
    __syncthreads();
    int cur = 0;
    for (int k0 = 32; k0 < HIDD; k0 += 32) {
        stage(cur ^ 1, k0);
        compute(cur);
        __syncthreads();
        cur ^= 1;
    }
    compute(cur);

    #pragma unroll
    for (int i = 0; i < 4; i++)
        #pragma unroll
        for (int j = 0; j < 8; j++)
            #pragma unroll
            for (int r = 0; r < 4; r++)
                acc[i][j][r] = exptanh(acc[i][j][r]);

    #pragma unroll
    for (int i = 0; i < 4; i++)
        #pragma unroll
        for (int r = 0; r < 4; r++) {
            const size_t rowbase =
                ((size_t)b * NQ + tile_q + wm + 16 * i + quad * 4 + r) * NV + tile_v;
            #pragma unroll
            for (int j = 0; j < 8; j++)
                Eg[rowbase + wn + 16 * j + fr] = (__bf16)acc[i][j][r];
        }

    // row sums over this wave's 128 cols -> R (reduce over fr)
    #pragma unroll
    for (int i = 0; i < 4; i++)
        #pragma unroll
        for (int r = 0; r < 4; r++) {
            float s = 0.f;
            #pragma unroll
            for (int j = 0; j < 8; j++) s += acc[i][j][r];
            s += __shfl_xor(s, 1); s += __shfl_xor(s, 2);
            s += __shfl_xor(s, 4); s += __shfl_xor(s, 8);
            if (fr == 0)
                atomicAdd(&R[b * NQ + tile_q + wm + 16 * i + quad * 4 + r], s);
        }
    // col sums over this wave's 64 rows -> C (reduce over quad)
    #pragma unroll
    for (int j = 0; j < 8; j++) {
        float s = 0.f;
        #pragma unroll
        for (int i = 0; i < 4; i++)
            #pragma unroll
            for (int r = 0; r < 4; r++) s += acc[i][j][r];
        s += __shfl_xor(s, 16); s += __shfl_xor(s, 32);
        if (quad == 0)
            atomicAdd(&Csum[b * NV + tile_v + wn + 16 * j + fr], s);
    }
}

// ---------------------------------------------------------------------------
// One E pass computes both marginals:
//   sv[b,v] = sum_q E[b,q,v]/R[b,q]   (LDS cross-wave reduce -> 1 atomic/(blk,v))
//   sq[b,q] = sum_v E[b,q,v]/C[b,v]   (wave-exclusive rows, direct write)
__global__ __launch_bounds__(512) void marg_k(
    const __bf16* __restrict__ E, const float* __restrict__ R,
    const float* __restrict__ C, float* __restrict__ sv,
    float* __restrict__ sq)
{
    __shared__ float sred[8][1024];   // 32 KB
    const int b  = blockIdx.y;
    const int q0 = blockIdx.x * 64;
    const int t = threadIdx.x, lane = t & 63, wave = t >> 6;
    const float* Cb = C + b * NV;
    float ci[2][8];
    float svp[2][8] = {};
    #pragma unroll
    for (int c = 0; c < 2; c++) {
        float4 c0 = *(const float4*)&Cb[c * 512 + lane * 8];
        float4 c1 = *(const float4*)&Cb[c * 512 + lane * 8 + 4];
        ci[c][0] = 1.0f / c0.x; ci[c][1] = 1.0f / c0.y;
        ci[c][2] = 1.0f / c0.z; ci[c][3] = 1.0f / c0.w;
        ci[c][4] = 1.0f / c1.x; ci[c][5] = 1.0f / c1.y;
        ci[c][6] = 1.0f / c1.z; ci[c][7] = 1.0f / c1.w;
    }
    const float* Rb = R + b * NQ + q0 + wave * 8;
    const __bf16* Ebase = E + ((size_t)b * NQ + q0 + wave * 8) * NV;
    #pragma unroll
    for (int rr = 0; rr < 8; rr++) {
        const __bf16* Erow = Ebase + (size_t)rr * NV;
        const float ri = 1.0f / Rb[rr];
        float p = 0.f;
        #pragma unroll
        for (int c = 0; c < 2; c++) {
            bf16x8 ev = *(const bf16x8*)&Erow[c * 512 + lane * 8];
            #pragma unroll
            for (int k = 0; k < 8; k++) {
                float e = (float)ev[k];
                svp[c][k] += e * ri;
                p += e * ci[c][k];
            }
        }
        p += __shfl_xor(p, 1);  p += __shfl_xor(p, 2);  p += __shfl_xor(p, 4);
        p += __shfl_xor(p, 8);  p += __shfl_xor(p, 16); p += __shfl_xor(p, 32);
        if (lane == 0) sq[b * NQ + q0 + wave * 8 + rr] = p;
    }
    #pragma unroll
    for (int c = 0; c < 2; c++) {
        float4 w0 = { svp[c][0], svp[c][1], svp[c][2], svp[c][3] };
        float4 w1 = { svp[c][4], svp[c][5], svp[c][6], svp[c][7] };
        *(float4*)&sred[wave][c * 512 + lane * 8]     = w0;
        *(float4*)&sred[wave][c * 512 + lane * 8 + 4] = w1;
    }
    __syncthreads();
    const int v = t * 2;
    float s0 = 0.f, s1 = 0.f;
    #pragma unroll
    for (int w = 0; w < 8; w++) { s0 += sred[w][v]; s1 += sred[w][v + 1]; }
    atomicAdd(&sv[b * NV + v],     s0);
    atomicAdd(&sv[b * NV + v + 1], s1);
}

// ---------------------------------------------------------------------------
// v_hat partials: vh_part[vs][b][d] = sum_{v in chunk} sv[b,v] * V[b,v,d]
__global__ __launch_bounds__(512) void vhat_k(const float* __restrict__ sv,
                                              const float* __restrict__ V,
                                              float* __restrict__ vh_part) {
    __shared__ float svl[256];
    __shared__ float4 red[4][128];
    const int b  = blockIdx.y;
    const int v0 = blockIdx.x * 256;
    const int t  = threadIdx.x;
    if (t < 256) svl[t] = sv[b * NV + v0 + t];
    __syncthreads();
    const int g = t >> 7, gi = t & 127;
    const float* Vb = V + ((size_t)b * NV + v0 + g) * VD + gi * 4;
    float4 a = {0.f, 0.f, 0.f, 0.f};
    #pragma unroll 8
    for (int i = 0; i < 64; i++) {
        const float s = svl[g + 4 * i];
        const float4 x = *(const float4*)(Vb + (size_t)(4 * i) * VD);
        a.x += s * x.x; a.y += s * x.y; a.z += s * x.z; a.w += s * x.w;
    }
    red[g][gi] = a;
    __syncthreads();
    if (t < 128) {
        float4 r0 = red[0][t], r1 = red[1][t], r2 = red[2][t], r3 = red[3][t];
        float4 o;
        o.x = r0.x + r1.x + r2.x + r3.x;
        o.y = r0.y + r1.y + r2.y + r3.y;
        o.z = r0.z + r1.z + r2.z + r3.z;
        o.w = r0.w + r1.w + r2.w + r3.w;
        *(float4*)&vh_part[((size_t)blockIdx.x * B_SZ + b) * VD + t * 4] = o;
    }
}

// q_hat partials: qh_part[qs][b][d] = sum_{q in chunk} sq[b,q] * Q[b,q,d]
__global__ __launch_bounds__(384) void qhat_k(const float* __restrict__ sq,
                                              const float* __restrict__ Q,
                                              float* __restrict__ qh_part) {
    __shared__ float sql[128];
    __shared__ float4 red[2][192];
    const int b  = blockIdx.y;
    const int q0 = blockIdx.x * 128;
    const int t  = threadIdx.x;
    if (t < 128) sql[t] = sq[b * NQ + q0 + t];
    __syncthreads();
    const int g = (t >= 192) ? 1 : 0, gi = t - g * 192;
    const float* Qb = Q + ((size_t)b * NQ + q0 + g) * QD + gi * 4;
    float4 a = {0.f, 0.f, 0.f, 0.f};
    #pragma unroll 8
    for (int i = 0; i < 64; i++) {
        const float s = sql[g + 2 * i];
        const float4 x = *(const float4*)(Qb + (size_t)(2 * i) * QD);
        a.x += s * x.x; a.y += s * x.y; a.z += s * x.z; a.w += s * x.w;
    }
    red[g][gi] = a;
    __syncthreads();
    if (t < 192) {
        float4 r0 = red[0][t], r1 = red[1][t];
        float4 o;
        o.x = r0.x + r1.x; o.y = r0.y + r1.y;
        o.z = r0.z + r1.z; o.w = r0.w + r1.w;
        *(float4*)&qh_part[((size_t)blockIdx.x * B_SZ + b) * QD + t * 4] = o;
    }
}

// combine partials -> out (writes every element; no out memset needed)
__global__ __launch_bounds__(256) void fin_k(const float* __restrict__ vh_part,
                                             const float* __restrict__ qh_part,
                                             float* __restrict__ out) {
    const int i = blockIdx.x * 256 + threadIdx.x;
    const int nv = B_SZ * VD;
    const int nq = B_SZ * QD;
    if (i < nv) {
        float s = 0.f;
        #pragma unroll
        for (int p = 0; p < 4; p++) s += vh_part[(size_t)p * nv + i];
        out[i] = s;
    } else if (i < nv + nq) {
        const int j = i - nv;
        float s = 0.f;
        #pragma unroll
        for (int p = 0; p < 4; p++) s += qh_part[(size_t)p * nq + j];
        out[i] = s;
    }
}

// ---------------------------------------------------------------------------
extern "C" void kernel_launch(void* const* d_in, const int* in_sizes, int n_in,
                              void* d_out, int out_size, void* d_ws, size_t ws_size,
                              hipStream_t stream) {
    const float* V    = (const float*)d_in[0];
    const float* Q    = (const float*)d_in[1];
    const float* Wq_w = (const float*)d_in[2];
    const float* Wq_b = (const float*)d_in[3];
    const float* Wv_w = (const float*)d_in[4];
    const float* Wv_b = (const float*)d_in[5];
    float* out = (float*)d_out;

    const size_t nQp = (size_t)B_SZ * NQ * HIDD;
    const size_t nVp = (size_t)B_SZ * NV * HIDD;
    const size_t nE  = (size_t)B_SZ * NQ * NV;
    const size_t nWq = (size_t)HIDD * QD;
    const size_t nWv = (size_t)HIDD * VD;
    __bf16* Qp = (__bf16*)d_ws;
    __bf16* Vp = Qp + nQp;
    __bf16* E  = Vp + nVp;
    float* R   = (float*)(E + nE);                 // B*NQ
    float* C   = R + (size_t)B_SZ * NQ;            // B*NV
    float* sv  = C + (size_t)B_SZ * NV;            // B*NV
    float* sq  = sv + (size_t)B_SZ * NV;           // B*NQ
    // weights live here during cvt+proj; vh_part/qh_part alias afterwards
    __bf16* Wq = (__bf16*)(sq + (size_t)B_SZ * NQ);
    __bf16* Wv = Wq + nWq;
    float* vh_part = (float*)Wq;                        // [4][B][VD]
    float* qh_part = vh_part + (size_t)4 * B_SZ * VD;   // [4][B][QD]
    size_t need = (nQp + nVp + nE + nWq + nWv) * 2 +
                  ((size_t)B_SZ * (NQ + NV) * 2) * 4;
    if (ws_size < need) return;

    // zero R, C, sv (contiguous); sq/out fully overwritten, no memset
    hipMemsetAsync(R, 0, ((size_t)B_SZ * (NQ + 2 * NV)) * sizeof(float), stream);

    cvt2_k<<<(int)((nWq + nWv) / 1024), 256, 0, stream>>>(
        Wq_w, Wv_w, Wq, (int)(nWq / 4), (int)((nWq + nWv) / 4));

    proj_k<<<(B_SZ * NQ) / 128 + (B_SZ * NV) / 128, 512, 0, stream>>>(
        Q, V, Wq, Wv, Wq_b, Wv_b, Qp, Vp);

    gemm_h<<<(NV / 256) * (NQ / 256) * B_SZ, 512, 0, stream>>>(Qp, Vp, E, R, C);

    marg_k<<<dim3(NQ / 64, B_SZ), 512, 0, stream>>>(E, R, C, sv, sq);

    vhat_k<<<dim3(NV / 256, B_SZ), 512, 0, stream>>>(sv, V, vh_part);
    qhat_k<<<dim3(NQ / 128, B_SZ), 384, 0, stream>>>(sq, Q, qh_part);

    fin_k<<<(B_SZ * (VD + QD) + 255) / 256, 256, 0, stream>>>(vh_part, qh_part, out);
}

// Round 4
// 478.927 us; speedup vs baseline: 1.9719x; 1.9719x over previous
//
#include <hip/hip_runtime.h>
#include <hip/hip_bf16.h>
#include <math.h>

#define B_SZ 64
#define NQ   512
#define NV   1024
#define QD   768
#define VD   512
#define HIDD 512

typedef __bf16 bf16x8 __attribute__((ext_vector_type(8)));
typedef __bf16 bf16x4 __attribute__((ext_vector_type(4)));
typedef float  floatx4 __attribute__((ext_vector_type(4)));

// async global->LDS, 16 bytes per lane; LDS dest is wave-uniform base,
// HW writes lane l at base + l*16 (linear). Swizzle applied on the global
// SOURCE col (gksw) + the LDS READ (fo) -- both-sides involution.
__device__ __forceinline__ void g2lds16(const __bf16* g, __bf16* l) {
    __builtin_amdgcn_global_load_lds((const __attribute__((address_space(1))) void*)g,
                                     (__attribute__((address_space(3))) void*)l,
                                     16, 0, 0);
}

// exp(tanh(s)) = e^(1 - 2/(e^{2s}+1)); saturates correctly as e^{2s}->0/inf.
__device__ __forceinline__ float exptanh(float s) {
    float t = __expf(2.0f * s);
    float r = __builtin_amdgcn_rcpf(t + 1.0f);
    return __expf(1.0f - 2.0f * r);
}

// ---------------------------------------------------------------------------
// fp32 -> bf16 convert for both weight matrices in one launch (dests adjacent).
__global__ __launch_bounds__(256) void cvt2_k(const float* __restrict__ s0,
                                              const float* __restrict__ s1,
                                              __bf16* __restrict__ d,
                                              int n4a, int n4tot) {
    int i = blockIdx.x * 256 + threadIdx.x;
    if (i >= n4tot) return;
    const float* s = (i < n4a) ? (s0 + (size_t)i * 4) : (s1 + (size_t)(i - n4a) * 4);
    float4 f = *(const float4*)s;
    bf16x4 o;
    o[0] = (__bf16)f.x; o[1] = (__bf16)f.y; o[2] = (__bf16)f.z; o[3] = (__bf16)f.w;
    *(bf16x4*)(d + (size_t)i * 4) = o;
}

// ---------------------------------------------------------------------------
// Projection GEMM, Q and V fused. Block = 64 rows x 256 cols (col half of
// the 512 outputs), 256 threads / 4 waves, each wave 64x64 (acc 4x4 = 64
// regs -- spill-safe at launch_bounds(256,4)). LDS 40 KB dbuf -> 4
// blocks/CU = 16 waves/CU (2x the R2 TLP; R2 was latency-bound at 8).
// Col-half is the grid LSB so the paired block's A re-read hits L2/L3.
__global__ __launch_bounds__(256, 4) void proj_k(
    const float* __restrict__ Qin, const float* __restrict__ Vin,
    const __bf16* __restrict__ Wqb, const __bf16* __restrict__ Wvb,
    const float* __restrict__ bq, const float* __restrict__ bv,
    __bf16* __restrict__ Qp, __bf16* __restrict__ Vp)
{
    __shared__ __bf16 As[2][64 * 32];    // 8 KB
    __shared__ __bf16 Bs[2][256 * 32];   // 32 KB
    const int nqblk = (B_SZ * NQ / 64) * 2;   // 1024
    const float* A; const __bf16* W; const float* bias; __bf16* Cout; int K, idx;
    if ((int)blockIdx.x < nqblk) {
        A = Qin; W = Wqb; bias = bq; Cout = Qp; K = QD; idx = blockIdx.x;
    } else {
        A = Vin; W = Wvb; bias = bv; Cout = Vp; K = VD; idx = blockIdx.x - nqblk;
    }
    const int mblk = idx >> 1, colhalf = idx & 1;

    const int t = threadIdx.x, lane = t & 63, wave = t >> 6;
    const int fr = lane & 15, quad = lane >> 4;
    const int fo   = (quad ^ ((fr >> 1) & 3)) * 8;            // swizzled frag read
    const int gksw = ((lane & 3) ^ ((lane >> 3) & 3)) * 8;    // pre-swizzled src col
    const int tile_m = mblk * 64;

    // W staging: wave stages its own 64 output cols (W rows) in 4 g2lds
    const __bf16* wsrc =
        W + (size_t)(colhalf * 256 + wave * 64 + (lane >> 2)) * K + gksw;
    // A staging: thread t handles row t>>2 (0..63), slot t&3 (8 fp32 elems)
    const int arow = t >> 2, aslot = t & 3;
    const float* ap = A + (size_t)(tile_m + arow) * K + aslot * 8;
    const int awoff = arow * 32 + ((aslot ^ ((arow >> 1) & 3)) * 8);

    floatx4 acc[4][4] = {};

    auto stage_w = [&](int p, int k0) {
        #pragma unroll
        for (int c = 0; c < 4; c++)
            g2lds16(wsrc + (size_t)(c * 16) * K + k0, &Bs[p][(wave * 64 + c * 16) * 32]);
    };
    auto cvt_a = [&](int p, float4 f0, float4 f1) {
        bf16x8 pk;
        pk[0] = (__bf16)f0.x; pk[1] = (__bf16)f0.y; pk[2] = (__bf16)f0.z; pk[3] = (__bf16)f0.w;
        pk[4] = (__bf16)f1.x; pk[5] = (__bf16)f1.y; pk[6] = (__bf16)f1.z; pk[7] = (__bf16)f1.w;
        *(bf16x8*)&As[p][awoff] = pk;
    };
    auto compute = [&](int p) {
        bf16x8 af[4];
        #pragma unroll
        for (int i = 0; i < 4; i++)
            af[i] = *(const bf16x8*)&As[p][(16 * i + fr) * 32 + fo];
        #pragma unroll
        for (int j = 0; j < 4; j++) {
            bf16x8 bg = *(const bf16x8*)&Bs[p][(wave * 64 + 16 * j + fr) * 32 + fo];
            #pragma unroll
            for (int i = 0; i < 4; i++)
                acc[i][j] = __builtin_amdgcn_mfma_f32_16x16x32_bf16(af[i], bg, acc[i][j], 0, 0, 0);
        }
    };

    {
        float4 f0 = *(const float4*)(ap);
        float4 f1 = *(const float4*)(ap + 4);
        stage_w(0, 0);
        cvt_a(0, f0, f1);
    }
    __syncthreads();
    int cur = 0;
    for (int k0 = 32; k0 < K; k0 += 32) {
        float4 f0 = *(const float4*)(ap + k0);       // A prefetch (global->reg)
        float4 f1 = *(const float4*)(ap + k0 + 4);
        const int nxt = cur ^ 1;
        stage_w(nxt, k0);                            // in flight across compute
        compute(cur);
        cvt_a(nxt, f0, f1);
        __syncthreads();
        cur = nxt;
    }
    compute(cur);

    #pragma unroll
    for (int j = 0; j < 4; j++) {
        const int col = colhalf * 256 + wave * 64 + 16 * j + fr;
        const float bvv = bias[col];
        #pragma unroll
        for (int i = 0; i < 4; i++)
            #pragma unroll
            for (int r = 0; r < 4; r++) {
                const int row = tile_m + 16 * i + quad * 4 + r;
                Cout[(size_t)row * HIDD + col] = (__bf16)(acc[i][j][r] + bvv);
            }
    }
}

// ---------------------------------------------------------------------------
// Per batch: S = Qp[b] @ Vp[b]^T on a 128x256 tile; E = exp(tanh(S)) -> bf16;
// row sums -> R, col sums -> C (atomics).   [verbatim R2 version]
__global__ __launch_bounds__(256, 2) void gemm_h(
    const __bf16* __restrict__ Qp, const __bf16* __restrict__ Vp,
    __bf16* __restrict__ Eg, float* __restrict__ R, float* __restrict__ Csum)
{
    __shared__ __bf16 As[2][128 * 32];   // 16 KB
    __shared__ __bf16 Bs[2][256 * 32];   // 32 KB
    const int b      = blockIdx.z;
    const int tile_q = blockIdx.y * 128;
    const int tile_v = blockIdx.x * 256;
    const int t = threadIdx.x, lane = t & 63, wave = t >> 6;
    const int fr = lane & 15, quad = lane >> 4;
    const int fo   = (quad ^ ((fr >> 1) & 3)) * 8;
    const int gksw = ((lane & 3) ^ ((lane >> 3) & 3)) * 8;
    const int wm = (wave >> 1) * 64, wn = (wave & 1) * 128;

    const __bf16* Aq = Qp + ((size_t)b * NQ + tile_q + wave * 16 + (lane >> 2)) * HIDD + gksw;
    const __bf16* Bv = Vp + ((size_t)b * NV + tile_v + wave * 16 + (lane >> 2)) * HIDD + gksw;

    auto stage = [&](int p, int k0) {
        #pragma unroll
        for (int c = 0; c < 2; c++)
            g2lds16(Aq + (size_t)(c * 64) * HIDD + k0, &As[p][(c * 64 + wave * 16) * 32]);
        #pragma unroll
        for (int c = 0; c < 4; c++)
            g2lds16(Bv + (size_t)(c * 64) * HIDD + k0, &Bs[p][(c * 64 + wave * 16) * 32]);
    };

    floatx4 acc[4][8] = {};
    auto compute = [&](int p) {
        bf16x8 af[4];
        #pragma unroll
        for (int i = 0; i < 4; i++)
            af[i] = *(const bf16x8*)&As[p][(wm + 16 * i + fr) * 32 + fo];
        #pragma unroll
        for (int j = 0; j < 8; j++) {
            bf16x8 bg = *(const bf16x8*)&Bs[p][(wn + 16 * j + fr) * 32 + fo];
            #pragma unroll
            for (int i = 0; i < 4; i++)
                acc[i][j] = __builtin_amdgcn_mfma_f32_16x16x32_bf16(af[i], bg, acc[i][j], 0, 0, 0);
        }
    };

    stage(0, 0);
    __syncthreads();
    int cur = 0;
    for (int k0 = 32; k0 < HIDD; k0 += 32) {
        stage(cur ^ 1, k0);
        compute(cur);
        __syncthreads();
        cur ^= 1;
    }
    compute(cur);

    #pragma unroll
    for (int i = 0; i < 4; i++)
        #pragma unroll
        for (int j = 0; j < 8; j++)
            #pragma unroll
            for (int r = 0; r < 4; r++)
                acc[i][j][r] = exptanh(acc[i][j][r]);

    #pragma unroll
    for (int i = 0; i < 4; i++)
        #pragma unroll
        for (int r = 0; r < 4; r++) {
            const size_t rowbase =
                ((size_t)b * NQ + tile_q + wm + 16 * i + quad * 4 + r) * NV + tile_v;
            #pragma unroll
            for (int j = 0; j < 8; j++)
                Eg[rowbase + wn + 16 * j + fr] = (__bf16)acc[i][j][r];
        }

    #pragma unroll
    for (int i = 0; i < 4; i++)
        #pragma unroll
        for (int r = 0; r < 4; r++) {
            float s = 0.f;
            #pragma unroll
            for (int j = 0; j < 8; j++) s += acc[i][j][r];
            s += __shfl_xor(s, 1); s += __shfl_xor(s, 2);
            s += __shfl_xor(s, 4); s += __shfl_xor(s, 8);
            if (fr == 0)
                atomicAdd(&R[b * NQ + tile_q + wm + 16 * i + quad * 4 + r], s);
        }
    #pragma unroll
    for (int j = 0; j < 8; j++) {
        float s = 0.f;
        #pragma unroll
        for (int i = 0; i < 4; i++)
            #pragma unroll
            for (int r = 0; r < 4; r++) s += acc[i][j][r];
        s += __shfl_xor(s, 16); s += __shfl_xor(s, 32);
        if (quad == 0)
            atomicAdd(&Csum[b * NV + tile_v + wn + 16 * j + fr], s);
    }
}

// ---------------------------------------------------------------------------
// One E pass computes both marginals:
//   sv[b,v] = sum_q E[b,q,v]/R[b,q]   (LDS cross-wave reduce -> 1 atomic/(blk,v))
//   sq[b,q] = sum_v E[b,q,v]/C[b,v]   (wave-exclusive rows, direct write)
__global__ __launch_bounds__(512) void marg_k(
    const __bf16* __restrict__ E, const float* __restrict__ R,
    const float* __restrict__ C, float* __restrict__ sv,
    float* __restrict__ sq)
{
    __shared__ float sred[8][1024];   // 32 KB
    const int b  = blockIdx.y;
    const int q0 = blockIdx.x * 64;
    const int t = threadIdx.x, lane = t & 63, wave = t >> 6;
    const float* Cb = C + b * NV;
    float ci[2][8];
    float svp[2][8] = {};
    #pragma unroll
    for (int c = 0; c < 2; c++) {
        float4 c0 = *(const float4*)&Cb[c * 512 + lane * 8];
        float4 c1 = *(const float4*)&Cb[c * 512 + lane * 8 + 4];
        ci[c][0] = 1.0f / c0.x; ci[c][1] = 1.0f / c0.y;
        ci[c][2] = 1.0f / c0.z; ci[c][3] = 1.0f / c0.w;
        ci[c][4] = 1.0f / c1.x; ci[c][5] = 1.0f / c1.y;
        ci[c][6] = 1.0f / c1.z; ci[c][7] = 1.0f / c1.w;
    }
    const float* Rb = R + b * NQ + q0 + wave * 8;
    const __bf16* Ebase = E + ((size_t)b * NQ + q0 + wave * 8) * NV;
    #pragma unroll
    for (int rr = 0; rr < 8; rr++) {
        const __bf16* Erow = Ebase + (size_t)rr * NV;
        const float ri = 1.0f / Rb[rr];
        float p = 0.f;
        #pragma unroll
        for (int c = 0; c < 2; c++) {
            bf16x8 ev = *(const bf16x8*)&Erow[c * 512 + lane * 8];
            #pragma unroll
            for (int k = 0; k < 8; k++) {
                float e = (float)ev[k];
                svp[c][k] += e * ri;
                p += e * ci[c][k];
            }
        }
        p += __shfl_xor(p, 1);  p += __shfl_xor(p, 2);  p += __shfl_xor(p, 4);
        p += __shfl_xor(p, 8);  p += __shfl_xor(p, 16); p += __shfl_xor(p, 32);
        if (lane == 0) sq[b * NQ + q0 + wave * 8 + rr] = p;
    }
    #pragma unroll
    for (int c = 0; c < 2; c++) {
        float4 w0 = { svp[c][0], svp[c][1], svp[c][2], svp[c][3] };
        float4 w1 = { svp[c][4], svp[c][5], svp[c][6], svp[c][7] };
        *(float4*)&sred[wave][c * 512 + lane * 8]     = w0;
        *(float4*)&sred[wave][c * 512 + lane * 8 + 4] = w1;
    }
    __syncthreads();
    const int v = t * 2;
    float s0 = 0.f, s1 = 0.f;
    #pragma unroll
    for (int w = 0; w < 8; w++) { s0 += sred[w][v]; s1 += sred[w][v + 1]; }
    atomicAdd(&sv[b * NV + v],     s0);
    atomicAdd(&sv[b * NV + v + 1], s1);
}

// ---------------------------------------------------------------------------
// v_hat partials: vh_part[vs][b][d] = sum_{v in chunk} sv[b,v] * V[b,v,d]
__global__ __launch_bounds__(512) void vhat_k(const float* __restrict__ sv,
                                              const float* __restrict__ V,
                                              float* __restrict__ vh_part) {
    __shared__ float svl[256];
    __shared__ float4 red[4][128];
    const int b  = blockIdx.y;
    const int v0 = blockIdx.x * 256;
    const int t  = threadIdx.x;
    if (t < 256) svl[t] = sv[b * NV + v0 + t];
    __syncthreads();
    const int g = t >> 7, gi = t & 127;
    const float* Vb = V + ((size_t)b * NV + v0 + g) * VD + gi * 4;
    float4 a = {0.f, 0.f, 0.f, 0.f};
    #pragma unroll 8
    for (int i = 0; i < 64; i++) {
        const float s = svl[g + 4 * i];
        const float4 x = *(const float4*)(Vb + (size_t)(4 * i) * VD);
        a.x += s * x.x; a.y += s * x.y; a.z += s * x.z; a.w += s * x.w;
    }
    red[g][gi] = a;
    __syncthreads();
    if (t < 128) {
        float4 r0 = red[0][t], r1 = red[1][t], r2 = red[2][t], r3 = red[3][t];
        float4 o;
        o.x = r0.x + r1.x + r2.x + r3.x;
        o.y = r0.y + r1.y + r2.y + r3.y;
        o.z = r0.z + r1.z + r2.z + r3.z;
        o.w = r0.w + r1.w + r2.w + r3.w;
        *(float4*)&vh_part[((size_t)blockIdx.x * B_SZ + b) * VD + t * 4] = o;
    }
}

// q_hat partials: qh_part[qs][b][d] = sum_{q in chunk} sq[b,q] * Q[b,q,d]
__global__ __launch_bounds__(384) void qhat_k(const float* __restrict__ sq,
                                              const float* __restrict__ Q,
                                              float* __restrict__ qh_part) {
    __shared__ float sql[128];
    __shared__ float4 red[2][192];
    const int b  = blockIdx.y;
    const int q0 = blockIdx.x * 128;
    const int t  = threadIdx.x;
    if (t < 128) sql[t] = sq[b * NQ + q0 + t];
    __syncthreads();
    const int g = (t >= 192) ? 1 : 0, gi = t - g * 192;
    const float* Qb = Q + ((size_t)b * NQ + q0 + g) * QD + gi * 4;
    float4 a = {0.f, 0.f, 0.f, 0.f};
    #pragma unroll 8
    for (int i = 0; i < 64; i++) {
        const float s = sql[g + 2 * i];
        const float4 x = *(const float4*)(Qb + (size_t)(2 * i) * QD);
        a.x += s * x.x; a.y += s * x.y; a.z += s * x.z; a.w += s * x.w;
    }
    red[g][gi] = a;
    __syncthreads();
    if (t < 192) {
        float4 r0 = red[0][t], r1 = red[1][t];
        float4 o;
        o.x = r0.x + r1.x; o.y = r0.y + r1.y;
        o.z = r0.z + r1.z; o.w = r0.w + r1.w;
        *(float4*)&qh_part[((size_t)blockIdx.x * B_SZ + b) * QD + t * 4] = o;
    }
}

// combine partials -> out (writes every element; no out memset needed)
__global__ __launch_bounds__(256) void fin_k(const float* __restrict__ vh_part,
                                             const float* __restrict__ qh_part,
                                             float* __restrict__ out) {
    const int i = blockIdx.x * 256 + threadIdx.x;
    const int nv = B_SZ * VD;
    const int nq = B_SZ * QD;
    if (i < nv) {
        float s = 0.f;
        #pragma unroll
        for (int p = 0; p < 4; p++) s += vh_part[(size_t)p * nv + i];
        out[i] = s;
    } else if (i < nv + nq) {
        const int j = i - nv;
        float s = 0.f;
        #pragma unroll
        for (int p = 0; p < 4; p++) s += qh_part[(size_t)p * nq + j];
        out[i] = s;
    }
}

// ---------------------------------------------------------------------------
extern "C" void kernel_launch(void* const* d_in, const int* in_sizes, int n_in,
                              void* d_out, int out_size, void* d_ws, size_t ws_size,
                              hipStream_t stream) {
    const float* V    = (const float*)d_in[0];
    const float* Q    = (const float*)d_in[1];
    const float* Wq_w = (const float*)d_in[2];
    const float* Wq_b = (const float*)d_in[3];
    const float* Wv_w = (const float*)d_in[4];
    const float* Wv_b = (const float*)d_in[5];
    float* out = (float*)d_out;

    const size_t nQp = (size_t)B_SZ * NQ * HIDD;
    const size_t nVp = (size_t)B_SZ * NV * HIDD;
    const size_t nE  = (size_t)B_SZ * NQ * NV;
    const size_t nWq = (size_t)HIDD * QD;
    const size_t nWv = (size_t)HIDD * VD;
    __bf16* Qp = (__bf16*)d_ws;
    __bf16* Vp = Qp + nQp;
    __bf16* E  = Vp + nVp;
    float* R   = (float*)(E + nE);                 // B*NQ
    float* C   = R + (size_t)B_SZ * NQ;            // B*NV
    float* sv  = C + (size_t)B_SZ * NV;            // B*NV
    float* sq  = sv + (size_t)B_SZ * NV;           // B*NQ
    // weights live here during cvt+proj; vh_part/qh_part alias afterwards
    __bf16* Wq = (__bf16*)(sq + (size_t)B_SZ * NQ);
    __bf16* Wv = Wq + nWq;
    float* vh_part = (float*)Wq;                        // [4][B][VD]
    float* qh_part = vh_part + (size_t)4 * B_SZ * VD;   // [4][B][QD]
    size_t need = (nQp + nVp + nE + nWq + nWv) * 2 +
                  ((size_t)B_SZ * (NQ + NV) * 2) * 4;
    if (ws_size < need) return;

    // zero R, C, sv (contiguous); sq/out fully overwritten, no memset
    hipMemsetAsync(R, 0, ((size_t)B_SZ * (NQ + 2 * NV)) * sizeof(float), stream);

    cvt2_k<<<(int)((nWq + nWv) / 1024), 256, 0, stream>>>(
        Wq_w, Wv_w, Wq, (int)(nWq / 4), (int)((nWq + nWv) / 4));

    proj_k<<<((B_SZ * NQ) / 64 + (B_SZ * NV) / 64) * 2, 256, 0, stream>>>(
        Q, V, Wq, Wv, Wq_b, Wv_b, Qp, Vp);

    gemm_h<<<dim3(NV / 256, NQ / 128, B_SZ), 256, 0, stream>>>(Qp, Vp, E, R, C);

    marg_k<<<dim3(NQ / 64, B_SZ), 512, 0, stream>>>(E, R, C, sv, sq);

    vhat_k<<<dim3(NV / 256, B_SZ), 512, 0, stream>>>(sv, V, vh_part);
    qhat_k<<<dim3(NQ / 128, B_SZ), 384, 0, stream>>>(sq, Q, qh_part);

    fin_k<<<(B_SZ * (VD + QD) + 255) / 256, 256, 0, stream>>>(vh_part, qh_part, out);
}

// Round 5
// 446.266 us; speedup vs baseline: 2.1162x; 1.0732x over previous
//
#include <hip/hip_runtime.h>
#include <hip/hip_bf16.h>
#include <math.h>

#define B_SZ 64
#define NQ   512
#define NV   1024
#define QD   768
#define VD   512
#define HIDD 512

typedef __bf16 bf16x8 __attribute__((ext_vector_type(8)));
typedef __bf16 bf16x4 __attribute__((ext_vector_type(4)));
typedef float  floatx4 __attribute__((ext_vector_type(4)));

// async global->LDS, 16 bytes per lane (used by gemm_h only now).
__device__ __forceinline__ void g2lds16(const __bf16* g, __bf16* l) {
    __builtin_amdgcn_global_load_lds((const __attribute__((address_space(1))) void*)g,
                                     (__attribute__((address_space(3))) void*)l,
                                     16, 0, 0);
}

// exp(tanh(s)) = e^(1 - 2/(e^{2s}+1)); saturates correctly as e^{2s}->0/inf.
__device__ __forceinline__ float exptanh(float s) {
    float t = __expf(2.0f * s);
    float r = __builtin_amdgcn_rcpf(t + 1.0f);
    return __expf(1.0f - 2.0f * r);
}

// lgkm-only barrier: LDS writes are visible, but global loads in flight are
// NOT drained (no vmcnt) -- the whole point of the reg-staged pipeline.
__device__ __forceinline__ void lds_barrier() {
    asm volatile("s_waitcnt lgkmcnt(0)" ::: "memory");
    __builtin_amdgcn_sched_barrier(0);
    __builtin_amdgcn_s_barrier();
}

// ---------------------------------------------------------------------------
// Convert + PRE-PACK both weight matrices into the exact per-K-step LDS image
// used by proj_k:  Wpk[step][R*32 + qsw*8 + e] = W[R][step*32 + q*8 + e],
// q = qsw ^ ((R>>1)&3)  (bank-swizzle baked in). Staging in proj_k is then a
// contiguous memcpy: lane t copies bytes [t*16) of each 8KB quarter-block.
__global__ __launch_bounds__(256) void cvtpack_k(const float* __restrict__ wq,
                                                 const float* __restrict__ wv,
                                                 __bf16* __restrict__ dq,
                                                 __bf16* __restrict__ dv) {
    const int i = blockIdx.x * 256 + threadIdx.x;
    const int nq8 = (HIDD * QD) / 8;            // 49152 threads for Q side
    const float* W; __bf16* d; int K, o;
    if (i < nq8) { W = wq; d = dq; K = QD; o = i * 8; }
    else         { W = wv; d = dv; K = VD; o = (i - nq8) * 8; }
    const int step = o >> 14;                   // / 16384 elems per k-step
    const int rem  = o & 16383;
    const int R    = rem >> 5;                  // W row (output col), 0..511
    const int qsw  = (rem >> 3) & 3;            // swizzled word slot
    const int q    = qsw ^ ((R >> 1) & 3);      // source k-word
    const float* src = W + (size_t)R * K + step * 32 + q * 8;
    float4 f0 = *(const float4*)src;
    float4 f1 = *(const float4*)(src + 4);
    bf16x8 pk;
    pk[0] = (__bf16)f0.x; pk[1] = (__bf16)f0.y; pk[2] = (__bf16)f0.z; pk[3] = (__bf16)f0.w;
    pk[4] = (__bf16)f1.x; pk[5] = (__bf16)f1.y; pk[6] = (__bf16)f1.z; pk[7] = (__bf16)f1.w;
    *(bf16x8*)(d + o) = pk;
}

// ---------------------------------------------------------------------------
// Projection GEMM, Q and V fused. Block = 128 rows x ALL 512 cols, 512 thr /
// 8 waves, wave 64x128 (acc 4x8). T14 async-STAGE pipeline:
//   regs hold step s+1 (W: 4x bf16x8 from prepacked image, contiguous loads;
//   A: 2x float4) -> ds_write to back buffer -> issue loads for s+2 ->
//   compute(front) -> lgkm-only barrier (vmcnt NOT drained).
// Global-load latency hides under compute; the barrier waits only on LDS.
__global__ __launch_bounds__(512, 2) void proj_k(
    const float* __restrict__ Qin, const float* __restrict__ Vin,
    const __bf16* __restrict__ Wqpk, const __bf16* __restrict__ Wvpk,
    const float* __restrict__ bq, const float* __restrict__ bv,
    __bf16* __restrict__ Qp, __bf16* __restrict__ Vp)
{
    __shared__ __bf16 As[2][128 * 32];   // 16 KB
    __shared__ __bf16 Bs[2][512 * 32];   // 64 KB
    const int nqblk = (B_SZ * NQ) / 128;   // 256
    const float* A; const __bf16* Wpk; const float* bias; __bf16* Cout; int K, mblk;
    if ((int)blockIdx.x < nqblk) {
        A = Qin; Wpk = Wqpk; bias = bq; Cout = Qp; K = QD; mblk = blockIdx.x;
    } else {
        A = Vin; Wpk = Wvpk; bias = bv; Cout = Vp; K = VD; mblk = blockIdx.x - nqblk;
    }
    const int nsteps = K / 32;             // 24 (Q) / 16 (V)

    const int t = threadIdx.x, lane = t & 63, wave = t >> 6;
    const int fr = lane & 15, quad = lane >> 4;
    const int fo = (quad ^ ((fr >> 1) & 3)) * 8;     // swizzled frag read
    const int tile_m = mblk * 128;
    const int wm = (wave >> 2) * 64;       // 0 / 64
    const int wn = (wave & 3) * 128;       // 0..384

    // A staging: thread t handles row t>>2 (0..127), slot t&3 (8 fp32)
    const int arow = t >> 2, aslot = t & 3;
    const float* ap = A + (size_t)(tile_m + arow) * K + aslot * 8;
    const int awoff = arow * 32 + ((aslot ^ ((arow >> 1) & 3)) * 8);
    // W staging: lane t copies elems [t*8, t*8+8) of each 4096-elem quarter
    const __bf16* wp = Wpk + t * 8;

    floatx4 acc[4][8] = {};
    bf16x8 wr0, wr1, wr2, wr3;             // step s+1 W image (16 VGPR)
    float4 af0, af1;                       // step s+1 A raw    (8 VGPR)

    auto loadW = [&](int s) {
        const __bf16* p = wp + (size_t)s * 16384;
        wr0 = *(const bf16x8*)(p);
        wr1 = *(const bf16x8*)(p + 4096);
        wr2 = *(const bf16x8*)(p + 8192);
        wr3 = *(const bf16x8*)(p + 12288);
    };
    auto loadA = [&](int s) {
        af0 = *(const float4*)(ap + s * 32);
        af1 = *(const float4*)(ap + s * 32 + 4);
    };
    auto stage = [&](int p) {
        *(bf16x8*)&Bs[p][t * 8]         = wr0;
        *(bf16x8*)&Bs[p][4096 + t * 8]  = wr1;
        *(bf16x8*)&Bs[p][8192 + t * 8]  = wr2;
        *(bf16x8*)&Bs[p][12288 + t * 8] = wr3;
        bf16x8 pk;
        pk[0] = (__bf16)af0.x; pk[1] = (__bf16)af0.y; pk[2] = (__bf16)af0.z; pk[3] = (__bf16)af0.w;
        pk[4] = (__bf16)af1.x; pk[5] = (__bf16)af1.y; pk[6] = (__bf16)af1.z; pk[7] = (__bf16)af1.w;
        *(bf16x8*)&As[p][awoff] = pk;
    };
    auto compute = [&](int p) {
        bf16x8 af[4];
        #pragma unroll
        for (int i = 0; i < 4; i++)
            af[i] = *(const bf16x8*)&As[p][(wm + 16 * i + fr) * 32 + fo];
        #pragma unroll
        for (int j = 0; j < 8; j++) {
            bf16x8 bg = *(const bf16x8*)&Bs[p][(wn + 16 * j + fr) * 32 + fo];
            #pragma unroll
            for (int i = 0; i < 4; i++)
                acc[i][j] = __builtin_amdgcn_mfma_f32_16x16x32_bf16(af[i], bg, acc[i][j], 0, 0, 0);
        }
    };

    // prologue: stage step 0, prefetch step 1
    loadW(0); loadA(0);
    stage(0);
    loadW(1); loadA(1);
    lds_barrier();

    int cur = 0;
    for (int s = 0; s < nsteps - 2; ++s) {
        stage(cur ^ 1);            // consume step-(s+1) regs (vmcnt-waited)
        loadW(s + 2); loadA(s + 2);// issue step-(s+2); NOT drained at barrier
        compute(cur);
        lds_barrier();
        cur ^= 1;
    }
    stage(cur ^ 1);                // last step (nsteps-1)
    compute(cur);
    lds_barrier();
    cur ^= 1;
    compute(cur);

    #pragma unroll
    for (int j = 0; j < 8; j++) {
        const int col = wn + 16 * j + fr;
        const float bvv = bias[col];
        #pragma unroll
        for (int i = 0; i < 4; i++)
            #pragma unroll
            for (int r = 0; r < 4; r++) {
                const int row = tile_m + wm + 16 * i + quad * 4 + r;
                Cout[(size_t)row * HIDD + col] = (__bf16)(acc[i][j][r] + bvv);
            }
    }
}

// ---------------------------------------------------------------------------
// Per batch: S = Qp[b] @ Vp[b]^T on a 128x256 tile; E = exp(tanh(S)) -> bf16;
// row sums -> R, col sums -> C (atomics).   [verbatim R2/R4 version]
__global__ __launch_bounds__(256, 2) void gemm_h(
    const __bf16* __restrict__ Qp, const __bf16* __restrict__ Vp,
    __bf16* __restrict__ Eg, float* __restrict__ R, float* __restrict__ Csum)
{
    __shared__ __bf16 As[2][128 * 32];   // 16 KB
    __shared__ __bf16 Bs[2][256 * 32];   // 32 KB
    const int b      = blockIdx.z;
    const int tile_q = blockIdx.y * 128;
    const int tile_v = blockIdx.x * 256;
    const int t = threadIdx.x, lane = t & 63, wave = t >> 6;
    const int fr = lane & 15, quad = lane >> 4;
    const int fo   = (quad ^ ((fr >> 1) & 3)) * 8;
    const int gksw = ((lane & 3) ^ ((lane >> 3) & 3)) * 8;
    const int wm = (wave >> 1) * 64, wn = (wave & 1) * 128;

    const __bf16* Aq = Qp + ((size_t)b * NQ + tile_q + wave * 16 + (lane >> 2)) * HIDD + gksw;
    const __bf16* Bv = Vp + ((size_t)b * NV + tile_v + wave * 16 + (lane >> 2)) * HIDD + gksw;

    auto stage = [&](int p, int k0) {
        #pragma unroll
        for (int c = 0; c < 2; c++)
            g2lds16(Aq + (size_t)(c * 64) * HIDD + k0, &As[p][(c * 64 + wave * 16) * 32]);
        #pragma unroll
        for (int c = 0; c < 4; c++)
            g2lds16(Bv + (size_t)(c * 64) * HIDD + k0, &Bs[p][(c * 64 + wave * 16) * 32]);
    };

    floatx4 acc[4][8] = {};
    auto compute = [&](int p) {
        bf16x8 af[4];
        #pragma unroll
        for (int i = 0; i < 4; i++)
            af[i] = *(const bf16x8*)&As[p][(wm + 16 * i + fr) * 32 + fo];
        #pragma unroll
        for (int j = 0; j < 8; j++) {
            bf16x8 bg = *(const bf16x8*)&Bs[p][(wn + 16 * j + fr) * 32 + fo];
            #pragma unroll
            for (int i = 0; i < 4; i++)
                acc[i][j] = __builtin_amdgcn_mfma_f32_16x16x32_bf16(af[i], bg, acc[i][j], 0, 0, 0);
        }
    };

    stage(0, 0);
    __syncthreads();
    int cur = 0;
    for (int k0 = 32; k0 < HIDD; k0 += 32) {
        stage(cur ^ 1, k0);
        compute(cur);
        __syncthreads();
        cur ^= 1;
    }
    compute(cur);

    #pragma unroll
    for (int i = 0; i < 4; i++)
        #pragma unroll
        for (int j = 0; j < 8; j++)
            #pragma unroll
            for (int r = 0; r < 4; r++)
                acc[i][j][r] = exptanh(acc[i][j][r]);

    #pragma unroll
    for (int i = 0; i < 4; i++)
        #pragma unroll
        for (int r = 0; r < 4; r++) {
            const size_t rowbase =
                ((size_t)b * NQ + tile_q + wm + 16 * i + quad * 4 + r) * NV + tile_v;
            #pragma unroll
            for (int j = 0; j < 8; j++)
                Eg[rowbase + wn + 16 * j + fr] = (__bf16)acc[i][j][r];
        }

    #pragma unroll
    for (int i = 0; i < 4; i++)
        #pragma unroll
        for (int r = 0; r < 4; r++) {
            float s = 0.f;
            #pragma unroll
            for (int j = 0; j < 8; j++) s += acc[i][j][r];
            s += __shfl_xor(s, 1); s += __shfl_xor(s, 2);
            s += __shfl_xor(s, 4); s += __shfl_xor(s, 8);
            if (fr == 0)
                atomicAdd(&R[b * NQ + tile_q + wm + 16 * i + quad * 4 + r], s);
        }
    #pragma unroll
    for (int j = 0; j < 8; j++) {
        float s = 0.f;
        #pragma unroll
        for (int i = 0; i < 4; i++)
            #pragma unroll
            for (int r = 0; r < 4; r++) s += acc[i][j][r];
        s += __shfl_xor(s, 16); s += __shfl_xor(s, 32);
        if (quad == 0)
            atomicAdd(&Csum[b * NV + tile_v + wn + 16 * j + fr], s);
    }
}

// ---------------------------------------------------------------------------
// One E pass computes both marginals:
//   sv[b,v] = sum_q E[b,q,v]/R[b,q]   (LDS cross-wave reduce -> 1 atomic/(blk,v))
//   sq[b,q] = sum_v E[b,q,v]/C[b,v]   (wave-exclusive rows, direct write)
__global__ __launch_bounds__(512) void marg_k(
    const __bf16* __restrict__ E, const float* __restrict__ R,
    const float* __restrict__ C, float* __restrict__ sv,
    float* __restrict__ sq)
{
    __shared__ float sred[8][1024];   // 32 KB
    const int b  = blockIdx.y;
    const int q0 = blockIdx.x * 64;
    const int t = threadIdx.x, lane = t & 63, wave = t >> 6;
    const float* Cb = C + b * NV;
    float ci[2][8];
    float svp[2][8] = {};
    #pragma unroll
    for (int c = 0; c < 2; c++) {
        float4 c0 = *(const float4*)&Cb[c * 512 + lane * 8];
        float4 c1 = *(const float4*)&Cb[c * 512 + lane * 8 + 4];
        ci[c][0] = 1.0f / c0.x; ci[c][1] = 1.0f / c0.y;
        ci[c][2] = 1.0f / c0.z; ci[c][3] = 1.0f / c0.w;
        ci[c][4] = 1.0f / c1.x; ci[c][5] = 1.0f / c1.y;
        ci[c][6] = 1.0f / c1.z; ci[c][7] = 1.0f / c1.w;
    }
    const float* Rb = R + b * NQ + q0 + wave * 8;
    const __bf16* Ebase = E + ((size_t)b * NQ + q0 + wave * 8) * NV;
    #pragma unroll
    for (int rr = 0; rr < 8; rr++) {
        const __bf16* Erow = Ebase + (size_t)rr * NV;
        const float ri = 1.0f / Rb[rr];
        float p = 0.f;
        #pragma unroll
        for (int c = 0; c < 2; c++) {
            bf16x8 ev = *(const bf16x8*)&Erow[c * 512 + lane * 8];
            #pragma unroll
            for (int k = 0; k < 8; k++) {
                float e = (float)ev[k];
                svp[c][k] += e * ri;
                p += e * ci[c][k];
            }
        }
        p += __shfl_xor(p, 1);  p += __shfl_xor(p, 2);  p += __shfl_xor(p, 4);
        p += __shfl_xor(p, 8);  p += __shfl_xor(p, 16); p += __shfl_xor(p, 32);
        if (lane == 0) sq[b * NQ + q0 + wave * 8 + rr] = p;
    }
    #pragma unroll
    for (int c = 0; c < 2; c++) {
        float4 w0 = { svp[c][0], svp[c][1], svp[c][2], svp[c][3] };
        float4 w1 = { svp[c][4], svp[c][5], svp[c][6], svp[c][7] };
        *(float4*)&sred[wave][c * 512 + lane * 8]     = w0;
        *(float4*)&sred[wave][c * 512 + lane * 8 + 4] = w1;
    }
    __syncthreads();
    const int v = t * 2;
    float s0 = 0.f, s1 = 0.f;
    #pragma unroll
    for (int w = 0; w < 8; w++) { s0 += sred[w][v]; s1 += sred[w][v + 1]; }
    atomicAdd(&sv[b * NV + v],     s0);
    atomicAdd(&sv[b * NV + v + 1], s1);
}

// ---------------------------------------------------------------------------
// v_hat partials: vh_part[vs][b][d] = sum_{v in chunk} sv[b,v] * V[b,v,d]
__global__ __launch_bounds__(512) void vhat_k(const float* __restrict__ sv,
                                              const float* __restrict__ V,
                                              float* __restrict__ vh_part) {
    __shared__ float svl[256];
    __shared__ float4 red[4][128];
    const int b  = blockIdx.y;
    const int v0 = blockIdx.x * 256;
    const int t  = threadIdx.x;
    if (t < 256) svl[t] = sv[b * NV + v0 + t];
    __syncthreads();
    const int g = t >> 7, gi = t & 127;
    const float* Vb = V + ((size_t)b * NV + v0 + g) * VD + gi * 4;
    float4 a = {0.f, 0.f, 0.f, 0.f};
    #pragma unroll 8
    for (int i = 0; i < 64; i++) {
        const float s = svl[g + 4 * i];
        const float4 x = *(const float4*)(Vb + (size_t)(4 * i) * VD);
        a.x += s * x.x; a.y += s * x.y; a.z += s * x.z; a.w += s * x.w;
    }
    red[g][gi] = a;
    __syncthreads();
    if (t < 128) {
        float4 r0 = red[0][t], r1 = red[1][t], r2 = red[2][t], r3 = red[3][t];
        float4 o;
        o.x = r0.x + r1.x + r2.x + r3.x;
        o.y = r0.y + r1.y + r2.y + r3.y;
        o.z = r0.z + r1.z + r2.z + r3.z;
        o.w = r0.w + r1.w + r2.w + r3.w;
        *(float4*)&vh_part[((size_t)blockIdx.x * B_SZ + b) * VD + t * 4] = o;
    }
}

// q_hat partials: qh_part[qs][b][d] = sum_{q in chunk} sq[b,q] * Q[b,q,d]
__global__ __launch_bounds__(384) void qhat_k(const float* __restrict__ sq,
                                              const float* __restrict__ Q,
                                              float* __restrict__ qh_part) {
    __shared__ float sql[128];
    __shared__ float4 red[2][192];
    const int b  = blockIdx.y;
    const int q0 = blockIdx.x * 128;
    const int t  = threadIdx.x;
    if (t < 128) sql[t] = sq[b * NQ + q0 + t];
    __syncthreads();
    const int g = (t >= 192) ? 1 : 0, gi = t - g * 192;
    const float* Qb = Q + ((size_t)b * NQ + q0 + g) * QD + gi * 4;
    float4 a = {0.f, 0.f, 0.f, 0.f};
    #pragma unroll 8
    for (int i = 0; i < 64; i++) {
        const float s = sql[g + 2 * i];
        const float4 x = *(const float4*)(Qb + (size_t)(2 * i) * QD);
        a.x += s * x.x; a.y += s * x.y; a.z += s * x.z; a.w += s * x.w;
    }
    red[g][gi] = a;
    __syncthreads();
    if (t < 192) {
        float4 r0 = red[0][t], r1 = red[1][t];
        float4 o;
        o.x = r0.x + r1.x; o.y = r0.y + r1.y;
        o.z = r0.z + r1.z; o.w = r0.w + r1.w;
        *(float4*)&qh_part[((size_t)blockIdx.x * B_SZ + b) * QD + t * 4] = o;
    }
}

// combine partials -> out (writes every element; no out memset needed)
__global__ __launch_bounds__(256) void fin_k(const float* __restrict__ vh_part,
                                             const float* __restrict__ qh_part,
                                             float* __restrict__ out) {
    const int i = blockIdx.x * 256 + threadIdx.x;
    const int nv = B_SZ * VD;
    const int nq = B_SZ * QD;
    if (i < nv) {
        float s = 0.f;
        #pragma unroll
        for (int p = 0; p < 4; p++) s += vh_part[(size_t)p * nv + i];
        out[i] = s;
    } else if (i < nv + nq) {
        const int j = i - nv;
        float s = 0.f;
        #pragma unroll
        for (int p = 0; p < 4; p++) s += qh_part[(size_t)p * nq + j];
        out[i] = s;
    }
}

// ---------------------------------------------------------------------------
extern "C" void kernel_launch(void* const* d_in, const int* in_sizes, int n_in,
                              void* d_out, int out_size, void* d_ws, size_t ws_size,
                              hipStream_t stream) {
    const float* V    = (const float*)d_in[0];
    const float* Q    = (const float*)d_in[1];
    const float* Wq_w = (const float*)d_in[2];
    const float* Wq_b = (const float*)d_in[3];
    const float* Wv_w = (const float*)d_in[4];
    const float* Wv_b = (const float*)d_in[5];
    float* out = (float*)d_out;

    const size_t nQp = (size_t)B_SZ * NQ * HIDD;
    const size_t nVp = (size_t)B_SZ * NV * HIDD;
    const size_t nE  = (size_t)B_SZ * NQ * NV;
    const size_t nWq = (size_t)HIDD * QD;
    const size_t nWv = (size_t)HIDD * VD;
    __bf16* Qp = (__bf16*)d_ws;
    __bf16* Vp = Qp + nQp;
    __bf16* E  = Vp + nVp;
    float* R   = (float*)(E + nE);                 // B*NQ
    float* C   = R + (size_t)B_SZ * NQ;            // B*NV
    float* sv  = C + (size_t)B_SZ * NV;            // B*NV
    float* sq  = sv + (size_t)B_SZ * NV;           // B*NQ
    // packed weights live here during cvt+proj; vh/qh partials alias after
    __bf16* Wq = (__bf16*)(sq + (size_t)B_SZ * NQ);
    __bf16* Wv = Wq + nWq;
    float* vh_part = (float*)Wq;                        // [4][B][VD]
    float* qh_part = vh_part + (size_t)4 * B_SZ * VD;   // [4][B][QD]
    size_t need = (nQp + nVp + nE + nWq + nWv) * 2 +
                  ((size_t)B_SZ * (NQ + NV) * 2) * 4;
    if (ws_size < need) return;

    // zero R, C, sv (contiguous); sq/out fully overwritten, no memset
    hipMemsetAsync(R, 0, ((size_t)B_SZ * (NQ + 2 * NV)) * sizeof(float), stream);

    cvtpack_k<<<(int)((nWq + nWv) / 8 / 256), 256, 0, stream>>>(Wq_w, Wv_w, Wq, Wv);

    proj_k<<<(B_SZ * NQ) / 128 + (B_SZ * NV) / 128, 512, 0, stream>>>(
        Q, V, Wq, Wv, Wq_b, Wv_b, Qp, Vp);

    gemm_h<<<dim3(NV / 256, NQ / 128, B_SZ), 256, 0, stream>>>(Qp, Vp, E, R, C);

    marg_k<<<dim3(NQ / 64, B_SZ), 512, 0, stream>>>(E, R, C, sv, sq);

    vhat_k<<<dim3(NV / 256, B_SZ), 512, 0, stream>>>(sv, V, vh_part);
    qhat_k<<<dim3(NQ / 128, B_SZ), 384, 0, stream>>>(sq, Q, qh_part);

    fin_k<<<(B_SZ * (VD + QD) + 255) / 256, 256, 0, stream>>>(vh_part, qh_part, out);
}

// Round 6
// 439.742 us; speedup vs baseline: 2.1476x; 1.0148x over previous
//
#include <hip/hip_runtime.h>
#include <hip/hip_bf16.h>
#include <math.h>

#define B_SZ 64
#define NQ   512
#define NV   1024
#define QD   768
#define VD   512
#define HIDD 512

typedef __bf16 bf16x8 __attribute__((ext_vector_type(8)));
typedef __bf16 bf16x4 __attribute__((ext_vector_type(4)));
typedef float  floatx4 __attribute__((ext_vector_type(4)));

// exp(tanh(s)) = e^(1 - 2/(e^{2s}+1)); saturates correctly as e^{2s}->0/inf.
__device__ __forceinline__ float exptanh(float s) {
    float t = __expf(2.0f * s);
    float r = __builtin_amdgcn_rcpf(t + 1.0f);
    return __expf(1.0f - 2.0f * r);
}

// lgkm-only barrier: LDS writes are visible, but global loads in flight are
// NOT drained (no vmcnt) -- the point of the reg-staged pipeline.
__device__ __forceinline__ void lds_barrier() {
    asm volatile("s_waitcnt lgkmcnt(0)" ::: "memory");
    __builtin_amdgcn_sched_barrier(0);
    __builtin_amdgcn_s_barrier();
}

// ---------------------------------------------------------------------------
// Convert + PRE-PACK both weight matrices into the exact per-K-step LDS image
// used by proj_k:  Wpk[step][R*32 + qsw*8 + e] = W[R][step*32 + q*8 + e],
// q = qsw ^ ((R>>1)&3)  (bank-swizzle baked in).
__global__ __launch_bounds__(256) void cvtpack_k(const float* __restrict__ wq,
                                                 const float* __restrict__ wv,
                                                 __bf16* __restrict__ dq,
                                                 __bf16* __restrict__ dv) {
    const int i = blockIdx.x * 256 + threadIdx.x;
    const int nq8 = (HIDD * QD) / 8;
    const float* W; __bf16* d; int K, o;
    if (i < nq8) { W = wq; d = dq; K = QD; o = i * 8; }
    else         { W = wv; d = dv; K = VD; o = (i - nq8) * 8; }
    const int step = o >> 14;
    const int rem  = o & 16383;
    const int R    = rem >> 5;
    const int qsw  = (rem >> 3) & 3;
    const int q    = qsw ^ ((R >> 1) & 3);
    const float* src = W + (size_t)R * K + step * 32 + q * 8;
    float4 f0 = *(const float4*)src;
    float4 f1 = *(const float4*)(src + 4);
    bf16x8 pk;
    pk[0] = (__bf16)f0.x; pk[1] = (__bf16)f0.y; pk[2] = (__bf16)f0.z; pk[3] = (__bf16)f0.w;
    pk[4] = (__bf16)f1.x; pk[5] = (__bf16)f1.y; pk[6] = (__bf16)f1.z; pk[7] = (__bf16)f1.w;
    *(bf16x8*)(d + o) = pk;
}

// ---------------------------------------------------------------------------
// Projection GEMM, Q and V fused. Block = 64 rows x ALL 512 cols, 512 thr /
// 8 waves, wave 32x128 (acc 2x8 = 64 regs, spill-safe under (512,4) cap).
// LDS 72 KB -> TWO independent blocks/CU: one block's MFMA phase hides the
// other's stage stall (intra-block TLP can't -- all waves share the barrier).
// R5's reg-staged lgkm-only pipeline kept verbatim.
__global__ __launch_bounds__(512, 4) void proj_k(
    const float* __restrict__ Qin, const float* __restrict__ Vin,
    const __bf16* __restrict__ Wqpk, const __bf16* __restrict__ Wvpk,
    const float* __restrict__ bq, const float* __restrict__ bv,
    __bf16* __restrict__ Qp, __bf16* __restrict__ Vp)
{
    __shared__ __bf16 As[2][64 * 32];    // 8 KB
    __shared__ __bf16 Bs[2][512 * 32];   // 64 KB -> 72 KB total
    const int nqblk = (B_SZ * NQ) / 64;   // 512
    const float* A; const __bf16* Wpk; const float* bias; __bf16* Cout; int K, mblk;
    if ((int)blockIdx.x < nqblk) {
        A = Qin; Wpk = Wqpk; bias = bq; Cout = Qp; K = QD; mblk = blockIdx.x;
    } else {
        A = Vin; Wpk = Wvpk; bias = bv; Cout = Vp; K = VD; mblk = blockIdx.x - nqblk;
    }
    const int nsteps = K / 32;             // 24 (Q) / 16 (V)

    const int t = threadIdx.x, lane = t & 63, wave = t >> 6;
    const int fr = lane & 15, quad = lane >> 4;
    const int fo = (quad ^ ((fr >> 1) & 3)) * 8;     // swizzled frag read
    const int tile_m = mblk * 64;
    const int wm = (wave >> 2) * 32;       // 0 / 32
    const int wn = (wave & 3) * 128;       // 0..384

    // A staging: 64x32 fp32 = 2048 elems, 4/thread: row t>>3, word (t>>1)&3,
    // half t&1. LDS image As[row*32 + qsw*8 + e], qsw = q ^ ((row>>1)&3).
    const int arow = t >> 3, aq = (t >> 1) & 3, ah = t & 1;
    const float* ap = A + (size_t)(tile_m + arow) * K + aq * 8 + ah * 4;
    const int awoff = arow * 32 + ((aq ^ ((arow >> 1) & 3)) * 8) + ah * 4;
    // W staging: prepacked image, 32 elems/thread in 4 contiguous chunks
    const __bf16* wp = Wpk + t * 8;

    floatx4 acc[2][8] = {};
    bf16x8 wr0, wr1, wr2, wr3;             // step s+1 W image (16 VGPR)
    float4 af;                             // step s+1 A raw    (4 VGPR)

    auto loadW = [&](int s) {
        const __bf16* p = wp + (size_t)s * 16384;
        wr0 = *(const bf16x8*)(p);
        wr1 = *(const bf16x8*)(p + 4096);
        wr2 = *(const bf16x8*)(p + 8192);
        wr3 = *(const bf16x8*)(p + 12288);
    };
    auto loadA = [&](int s) {
        af = *(const float4*)(ap + s * 32);
    };
    auto stage = [&](int p) {
        *(bf16x8*)&Bs[p][t * 8]         = wr0;
        *(bf16x8*)&Bs[p][4096 + t * 8]  = wr1;
        *(bf16x8*)&Bs[p][8192 + t * 8]  = wr2;
        *(bf16x8*)&Bs[p][12288 + t * 8] = wr3;
        bf16x4 pk;
        pk[0] = (__bf16)af.x; pk[1] = (__bf16)af.y;
        pk[2] = (__bf16)af.z; pk[3] = (__bf16)af.w;
        *(bf16x4*)&As[p][awoff] = pk;
    };
    auto compute = [&](int p) {
        bf16x8 afr[2];
        #pragma unroll
        for (int i = 0; i < 2; i++)
            afr[i] = *(const bf16x8*)&As[p][(wm + 16 * i + fr) * 32 + fo];
        #pragma unroll
        for (int j = 0; j < 8; j++) {
            bf16x8 bg = *(const bf16x8*)&Bs[p][(wn + 16 * j + fr) * 32 + fo];
            #pragma unroll
            for (int i = 0; i < 2; i++)
                acc[i][j] = __builtin_amdgcn_mfma_f32_16x16x32_bf16(afr[i], bg, acc[i][j], 0, 0, 0);
        }
    };

    loadW(0); loadA(0);
    stage(0);
    loadW(1); loadA(1);
    lds_barrier();

    int cur = 0;
    for (int s = 0; s < nsteps - 2; ++s) {
        stage(cur ^ 1);             // consume step-(s+1) regs (vmcnt-waited)
        loadW(s + 2); loadA(s + 2); // issue step-(s+2); NOT drained at barrier
        compute(cur);
        lds_barrier();
        cur ^= 1;
    }
    stage(cur ^ 1);
    compute(cur);
    lds_barrier();
    cur ^= 1;
    compute(cur);

    #pragma unroll
    for (int j = 0; j < 8; j++) {
        const int col = wn + 16 * j + fr;
        const float bvv = bias[col];
        #pragma unroll
        for (int i = 0; i < 2; i++)
            #pragma unroll
            for (int r = 0; r < 4; r++) {
                const int row = tile_m + wm + 16 * i + quad * 4 + r;
                Cout[(size_t)row * HIDD + col] = (__bf16)(acc[i][j][r] + bvv);
            }
    }
}

// ---------------------------------------------------------------------------
// Per batch: S = Qp[b] @ Vp[b]^T on a 128x256 tile, 512 thr / 8 waves
// (wave 32x128, acc 2x8); E = exp(tanh(S)) -> bf16; row sums -> R, col
// sums -> C (atomics). Same reg-staged lgkm-only pipeline as proj_k;
// LDS 48 KB -> 2+ independent blocks/CU.
__global__ __launch_bounds__(512, 4) void gemm_h(
    const __bf16* __restrict__ Qp, const __bf16* __restrict__ Vp,
    __bf16* __restrict__ Eg, float* __restrict__ R, float* __restrict__ Csum)
{
    __shared__ __bf16 As[2][128 * 32];   // 16 KB
    __shared__ __bf16 Bs[2][256 * 32];   // 32 KB
    const int b      = blockIdx.z;
    const int tile_q = blockIdx.y * 128;
    const int tile_v = blockIdx.x * 256;
    const int t = threadIdx.x, lane = t & 63, wave = t >> 6;
    const int fr = lane & 15, quad = lane >> 4;
    const int fo = (quad ^ ((fr >> 1) & 3)) * 8;
    const int wm = (wave >> 1) * 32, wn = (wave & 1) * 128;

    // staging: LDS slot t*8 <- source word pre-swizzled (both-sides pair).
    // A: row t>>2 (0..127); B: rows t>>2 and t>>2+128 (swizzle invariant:
    // (row+128)>>1 & 3 == row>>1 & 3).
    const int srow = t >> 2;
    const int scol = ((t & 3) ^ ((srow >> 1) & 3)) * 8;
    const __bf16* aps = Qp + ((size_t)b * NQ + tile_q + srow) * HIDD + scol;
    const __bf16* bps = Vp + ((size_t)b * NV + tile_v + srow) * HIDD + scol;
    const __bf16* bps2 = bps + (size_t)128 * HIDD;

    floatx4 acc[2][8] = {};
    bf16x8 ar, br0, br1;                   // step s+1 tiles (12 VGPR)

    auto loadAB = [&](int s) {
        ar  = *(const bf16x8*)(aps  + s * 32);
        br0 = *(const bf16x8*)(bps  + s * 32);
        br1 = *(const bf16x8*)(bps2 + s * 32);
    };
    auto stage = [&](int p) {
        *(bf16x8*)&As[p][t * 8]        = ar;
        *(bf16x8*)&Bs[p][t * 8]        = br0;
        *(bf16x8*)&Bs[p][4096 + t * 8] = br1;
    };
    auto compute = [&](int p) {
        bf16x8 afr[2];
        #pragma unroll
        for (int i = 0; i < 2; i++)
            afr[i] = *(const bf16x8*)&As[p][(wm + 16 * i + fr) * 32 + fo];
        #pragma unroll
        for (int j = 0; j < 8; j++) {
            bf16x8 bg = *(const bf16x8*)&Bs[p][(wn + 16 * j + fr) * 32 + fo];
            #pragma unroll
            for (int i = 0; i < 2; i++)
                acc[i][j] = __builtin_amdgcn_mfma_f32_16x16x32_bf16(afr[i], bg, acc[i][j], 0, 0, 0);
        }
    };

    loadAB(0);
    stage(0);
    loadAB(1);
    lds_barrier();
    int cur = 0;
    for (int s = 0; s < (HIDD / 32) - 2; ++s) {
        stage(cur ^ 1);
        loadAB(s + 2);
        compute(cur);
        lds_barrier();
        cur ^= 1;
    }
    stage(cur ^ 1);
    compute(cur);
    lds_barrier();
    cur ^= 1;
    compute(cur);

    #pragma unroll
    for (int i = 0; i < 2; i++)
        #pragma unroll
        for (int j = 0; j < 8; j++)
            #pragma unroll
            for (int r = 0; r < 4; r++)
                acc[i][j][r] = exptanh(acc[i][j][r]);

    #pragma unroll
    for (int i = 0; i < 2; i++)
        #pragma unroll
        for (int r = 0; r < 4; r++) {
            const size_t rowbase =
                ((size_t)b * NQ + tile_q + wm + 16 * i + quad * 4 + r) * NV + tile_v;
            #pragma unroll
            for (int j = 0; j < 8; j++)
                Eg[rowbase + wn + 16 * j + fr] = (__bf16)acc[i][j][r];
        }

    // row sums over this wave's 128 cols -> R (reduce over fr)
    #pragma unroll
    for (int i = 0; i < 2; i++)
        #pragma unroll
        for (int r = 0; r < 4; r++) {
            float s = 0.f;
            #pragma unroll
            for (int j = 0; j < 8; j++) s += acc[i][j][r];
            s += __shfl_xor(s, 1); s += __shfl_xor(s, 2);
            s += __shfl_xor(s, 4); s += __shfl_xor(s, 8);
            if (fr == 0)
                atomicAdd(&R[b * NQ + tile_q + wm + 16 * i + quad * 4 + r], s);
        }
    // col sums over this wave's 32 rows -> C (reduce over quad)
    #pragma unroll
    for (int j = 0; j < 8; j++) {
        float s = 0.f;
        #pragma unroll
        for (int i = 0; i < 2; i++)
            #pragma unroll
            for (int r = 0; r < 4; r++) s += acc[i][j][r];
        s += __shfl_xor(s, 16); s += __shfl_xor(s, 32);
        if (quad == 0)
            atomicAdd(&Csum[b * NV + tile_v + wn + 16 * j + fr], s);
    }
}

// ---------------------------------------------------------------------------
// One E pass computes both marginals:
//   sv[b,v] = sum_q E[b,q,v]/R[b,q]   (LDS cross-wave reduce -> 1 atomic/(blk,v))
//   sq[b,q] = sum_v E[b,q,v]/C[b,v]   (wave-exclusive rows, direct write)
__global__ __launch_bounds__(512) void marg_k(
    const __bf16* __restrict__ E, const float* __restrict__ R,
    const float* __restrict__ C, float* __restrict__ sv,
    float* __restrict__ sq)
{
    __shared__ float sred[8][1024];   // 32 KB
    const int b  = blockIdx.y;
    const int q0 = blockIdx.x * 64;
    const int t = threadIdx.x, lane = t & 63, wave = t >> 6;
    const float* Cb = C + b * NV;
    float ci[2][8];
    float svp[2][8] = {};
    #pragma unroll
    for (int c = 0; c < 2; c++) {
        float4 c0 = *(const float4*)&Cb[c * 512 + lane * 8];
        float4 c1 = *(const float4*)&Cb[c * 512 + lane * 8 + 4];
        ci[c][0] = 1.0f / c0.x; ci[c][1] = 1.0f / c0.y;
        ci[c][2] = 1.0f / c0.z; ci[c][3] = 1.0f / c0.w;
        ci[c][4] = 1.0f / c1.x; ci[c][5] = 1.0f / c1.y;
        ci[c][6] = 1.0f / c1.z; ci[c][7] = 1.0f / c1.w;
    }
    const float* Rb = R + b * NQ + q0 + wave * 8;
    const __bf16* Ebase = E + ((size_t)b * NQ + q0 + wave * 8) * NV;
    #pragma unroll
    for (int rr = 0; rr < 8; rr++) {
        const __bf16* Erow = Ebase + (size_t)rr * NV;
        const float ri = 1.0f / Rb[rr];
        float p = 0.f;
        #pragma unroll
        for (int c = 0; c < 2; c++) {
            bf16x8 ev = *(const bf16x8*)&Erow[c * 512 + lane * 8];
            #pragma unroll
            for (int k = 0; k < 8; k++) {
                float e = (float)ev[k];
                svp[c][k] += e * ri;
                p += e * ci[c][k];
            }
        }
        p += __shfl_xor(p, 1);  p += __shfl_xor(p, 2);  p += __shfl_xor(p, 4);
        p += __shfl_xor(p, 8);  p += __shfl_xor(p, 16); p += __shfl_xor(p, 32);
        if (lane == 0) sq[b * NQ + q0 + wave * 8 + rr] = p;
    }
    #pragma unroll
    for (int c = 0; c < 2; c++) {
        float4 w0 = { svp[c][0], svp[c][1], svp[c][2], svp[c][3] };
        float4 w1 = { svp[c][4], svp[c][5], svp[c][6], svp[c][7] };
        *(float4*)&sred[wave][c * 512 + lane * 8]     = w0;
        *(float4*)&sred[wave][c * 512 + lane * 8 + 4] = w1;
    }
    __syncthreads();
    const int v = t * 2;
    float s0 = 0.f, s1 = 0.f;
    #pragma unroll
    for (int w = 0; w < 8; w++) { s0 += sred[w][v]; s1 += sred[w][v + 1]; }
    atomicAdd(&sv[b * NV + v],     s0);
    atomicAdd(&sv[b * NV + v + 1], s1);
}

// ---------------------------------------------------------------------------
// v_hat partials: vh_part[vs][b][d] = sum_{v in chunk} sv[b,v] * V[b,v,d]
__global__ __launch_bounds__(512) void vhat_k(const float* __restrict__ sv,
                                              const float* __restrict__ V,
                                              float* __restrict__ vh_part) {
    __shared__ float svl[256];
    __shared__ float4 red[4][128];
    const int b  = blockIdx.y;
    const int v0 = blockIdx.x * 256;
    const int t  = threadIdx.x;
    if (t < 256) svl[t] = sv[b * NV + v0 + t];
    __syncthreads();
    const int g = t >> 7, gi = t & 127;
    const float* Vb = V + ((size_t)b * NV + v0 + g) * VD + gi * 4;
    float4 a = {0.f, 0.f, 0.f, 0.f};
    #pragma unroll 8
    for (int i = 0; i < 64; i++) {
        const float s = svl[g + 4 * i];
        const float4 x = *(const float4*)(Vb + (size_t)(4 * i) * VD);
        a.x += s * x.x; a.y += s * x.y; a.z += s * x.z; a.w += s * x.w;
    }
    red[g][gi] = a;
    __syncthreads();
    if (t < 128) {
        float4 r0 = red[0][t], r1 = red[1][t], r2 = red[2][t], r3 = red[3][t];
        float4 o;
        o.x = r0.x + r1.x + r2.x + r3.x;
        o.y = r0.y + r1.y + r2.y + r3.y;
        o.z = r0.z + r1.z + r2.z + r3.z;
        o.w = r0.w + r1.w + r2.w + r3.w;
        *(float4*)&vh_part[((size_t)blockIdx.x * B_SZ + b) * VD + t * 4] = o;
    }
}

// q_hat partials: qh_part[qs][b][d] = sum_{q in chunk} sq[b,q] * Q[b,q,d]
__global__ __launch_bounds__(384) void qhat_k(const float* __restrict__ sq,
                                              const float* __restrict__ Q,
                                              float* __restrict__ qh_part) {
    __shared__ float sql[128];
    __shared__ float4 red[2][192];
    const int b  = blockIdx.y;
    const int q0 = blockIdx.x * 128;
    const int t  = threadIdx.x;
    if (t < 128) sql[t] = sq[b * NQ + q0 + t];
    __syncthreads();
    const int g = (t >= 192) ? 1 : 0, gi = t - g * 192;
    const float* Qb = Q + ((size_t)b * NQ + q0 + g) * QD + gi * 4;
    float4 a = {0.f, 0.f, 0.f, 0.f};
    #pragma unroll 8
    for (int i = 0; i < 64; i++) {
        const float s = sql[g + 2 * i];
        const float4 x = *(const float4*)(Qb + (size_t)(2 * i) * QD);
        a.x += s * x.x; a.y += s * x.y; a.z += s * x.z; a.w += s * x.w;
    }
    red[g][gi] = a;
    __syncthreads();
    if (t < 192) {
        float4 r0 = red[0][t], r1 = red[1][t];
        float4 o;
        o.x = r0.x + r1.x; o.y = r0.y + r1.y;
        o.z = r0.z + r1.z; o.w = r0.w + r1.w;
        *(float4*)&qh_part[((size_t)blockIdx.x * B_SZ + b) * QD + t * 4] = o;
    }
}

// combine partials -> out (writes every element; no out memset needed)
__global__ __launch_bounds__(256) void fin_k(const float* __restrict__ vh_part,
                                             const float* __restrict__ qh_part,
                                             float* __restrict__ out) {
    const int i = blockIdx.x * 256 + threadIdx.x;
    const int nv = B_SZ * VD;
    const int nq = B_SZ * QD;
    if (i < nv) {
        float s = 0.f;
        #pragma unroll
        for (int p = 0; p < 4; p++) s += vh_part[(size_t)p * nv + i];
        out[i] = s;
    } else if (i < nv + nq) {
        const int j = i - nv;
        float s = 0.f;
        #pragma unroll
        for (int p = 0; p < 4; p++) s += qh_part[(size_t)p * nq + j];
        out[i] = s;
    }
}

// ---------------------------------------------------------------------------
extern "C" void kernel_launch(void* const* d_in, const int* in_sizes, int n_in,
                              void* d_out, int out_size, void* d_ws, size_t ws_size,
                              hipStream_t stream) {
    const float* V    = (const float*)d_in[0];
    const float* Q    = (const float*)d_in[1];
    const float* Wq_w = (const float*)d_in[2];
    const float* Wq_b = (const float*)d_in[3];
    const float* Wv_w = (const float*)d_in[4];
    const float* Wv_b = (const float*)d_in[5];
    float* out = (float*)d_out;

    const size_t nQp = (size_t)B_SZ * NQ * HIDD;
    const size_t nVp = (size_t)B_SZ * NV * HIDD;
    const size_t nE  = (size_t)B_SZ * NQ * NV;
    const size_t nWq = (size_t)HIDD * QD;
    const size_t nWv = (size_t)HIDD * VD;
    __bf16* Qp = (__bf16*)d_ws;
    __bf16* Vp = Qp + nQp;
    __bf16* E  = Vp + nVp;
    float* R   = (float*)(E + nE);                 // B*NQ
    float* C   = R + (size_t)B_SZ * NQ;            // B*NV
    float* sv  = C + (size_t)B_SZ * NV;            // B*NV
    float* sq  = sv + (size_t)B_SZ * NV;           // B*NQ
    // packed weights live here during cvt+proj; vh/qh partials alias after
    __bf16* Wq = (__bf16*)(sq + (size_t)B_SZ * NQ);
    __bf16* Wv = Wq + nWq;
    float* vh_part = (float*)Wq;                        // [4][B][VD]
    float* qh_part = vh_part + (size_t)4 * B_SZ * VD;   // [4][B][QD]
    size_t need = (nQp + nVp + nE + nWq + nWv) * 2 +
                  ((size_t)B_SZ * (NQ + NV) * 2) * 4;
    if (ws_size < need) return;

    // zero R, C, sv (contiguous); sq/out fully overwritten, no memset
    hipMemsetAsync(R, 0, ((size_t)B_SZ * (NQ + 2 * NV)) * sizeof(float), stream);

    cvtpack_k<<<(int)((nWq + nWv) / 8 / 256), 256, 0, stream>>>(Wq_w, Wv_w, Wq, Wv);

    proj_k<<<(B_SZ * NQ) / 64 + (B_SZ * NV) / 64, 512, 0, stream>>>(
        Q, V, Wq, Wv, Wq_b, Wv_b, Qp, Vp);

    gemm_h<<<dim3(NV / 256, NQ / 128, B_SZ), 512, 0, stream>>>(Qp, Vp, E, R, C);

    marg_k<<<dim3(NQ / 64, B_SZ), 512, 0, stream>>>(E, R, C, sv, sq);

    vhat_k<<<dim3(NV / 256, B_SZ), 512, 0, stream>>>(sv, V, vh_part);
    qhat_k<<<dim3(NQ / 128, B_SZ), 384, 0, stream>>>(sq, Q, qh_part);

    fin_k<<<(B_SZ * (VD + QD) + 255) / 256, 256, 0, stream>>>(vh_part, qh_part, out);
}